// Round 3
// baseline (43.589 us; speedup 1.0000x reference)
//
#include <hip/hip_runtime.h>

#define SCALE 64.0f
#define MARGIN 0.5f

constexpr int BLOCK = 256;
constexpr int GPT = 2;  // float4-groups per thread

// cos(x) radians via HW TRANS pipe (v_cos_f32 takes revolutions).
__device__ __forceinline__ float cos_fast(float x) {
    float r = x * 0.15915494309189535f;   // radians -> revolutions
    r = r - floorf(r);                    // v_fract_f32
    return __builtin_amdgcn_cosf(r);      // v_cos_f32
}

__device__ __forceinline__ float sample_loss(float d0, float d1, int lab) {
    float pos = lab ? d1 : d0;
    float neg = lab ? d0 : d1;
    float c1 = cos_fast(pos + MARGIN);
    float c0 = cos_fast(neg);
    float d  = (c0 - c1) * SCALE;         // ln - lp
    float t  = __expf(-fabsf(d));         // v_exp_f32
    float s  = __logf(1.0f + t);          // v_log_f32
    return fmaxf(d, 0.0f) + s;            // softplus(d)
}

__device__ __forceinline__ float quad_loss(float4 a, float4 b, int4 l) {
    float acc;
    acc  = sample_loss(a.x, b.x, l.x);
    acc += sample_loss(a.y, b.y, l.y);
    acc += sample_loss(a.z, b.z, l.z);
    acc += sample_loss(a.w, b.w, l.w);
    return acc;
}

__device__ __forceinline__ float block_reduce(float acc) {
    #pragma unroll
    for (int off = 32; off > 0; off >>= 1)
        acc += __shfl_down(acc, off, 64);
    __shared__ float warp_sums[BLOCK / 64];
    int wave = threadIdx.x >> 6;
    int lane = threadIdx.x & 63;
    if (lane == 0) warp_sums[wave] = acc;
    __syncthreads();
    if (threadIdx.x == 0) {
        float s = warp_sums[0];
        #pragma unroll
        for (int w = 1; w < BLOCK / 64; ++w) s += warp_sums[w];
        return s;
    }
    return 0.0f;
}

__global__ __launch_bounds__(BLOCK) void loss_partial_kernel(
    const float* __restrict__ dist, const int* __restrict__ label,
    float* __restrict__ partial, int n)
{
    const int ngroups = n >> 2;  // float4 groups (N = 2^24 -> 4M)
    const float4* __restrict__ row0 = reinterpret_cast<const float4*>(dist);
    const float4* __restrict__ row1 = reinterpret_cast<const float4*>(dist + n);
    const int4*   __restrict__ lab4 = reinterpret_cast<const int4*>(label);

    const int g0 = blockIdx.x * (BLOCK * GPT) + threadIdx.x;
    const int g1 = g0 + BLOCK;

    float acc = 0.0f;
    if (g1 < ngroups) {
        // 6 independent 16B loads, all issued before any use -> 6 in flight/wave
        float4 a0 = row0[g0];
        float4 a1 = row0[g1];
        float4 b0 = row1[g0];
        float4 b1 = row1[g1];
        int4   l0 = lab4[g0];
        int4   l1 = lab4[g1];
        acc  = quad_loss(a0, b0, l0);
        acc += quad_loss(a1, b1, l1);
    } else if (g0 < ngroups) {
        acc = quad_loss(row0[g0], row1[g0], lab4[g0]);
    }

    float s = block_reduce(acc);
    if (threadIdx.x == 0) partial[blockIdx.x] = s;
}

__global__ __launch_bounds__(BLOCK) void reduce_partials_kernel(
    const float* __restrict__ partial, float* __restrict__ out, int nparts)
{
    float acc = 0.0f;
    for (int i = threadIdx.x; i < nparts; i += BLOCK) acc += partial[i];
    float s = block_reduce(acc);
    if (threadIdx.x == 0) out[0] = s;
}

extern "C" void kernel_launch(void* const* d_in, const int* in_sizes, int n_in,
                              void* d_out, int out_size, void* d_ws, size_t ws_size,
                              hipStream_t stream) {
    const float* dist  = (const float*)d_in[0];
    const int*   label = (const int*)d_in[1];
    float* out = (float*)d_out;
    float* partial = (float*)d_ws;

    const int n = in_sizes[0] / 2;          // N samples (dist is 2 x N)
    const int ngroups = n >> 2;             // float4 groups
    const int grid = (ngroups + BLOCK * GPT - 1) / (BLOCK * GPT);  // 8192 for N=2^24

    loss_partial_kernel<<<grid, BLOCK, 0, stream>>>(dist, label, partial, n);
    reduce_partials_kernel<<<1, BLOCK, 0, stream>>>(partial, out, grid);
}

// Round 4
// 38.206 us; speedup vs baseline: 1.1409x; 1.1409x over previous
//
#include <hip/hip_runtime.h>

#define SCALE 64.0f
#define MARGIN 0.5f

constexpr int BLOCK = 256;
constexpr int GPT = 4;  // float4-groups per thread -> 12 independent 16B loads

// cos(x) radians via HW TRANS pipe (v_cos_f32 takes revolutions).
__device__ __forceinline__ float cos_fast(float x) {
    float r = x * 0.15915494309189535f;   // radians -> revolutions
    r = r - floorf(r);                    // v_fract_f32
    return __builtin_amdgcn_cosf(r);      // v_cos_f32
}

__device__ __forceinline__ float sample_loss(float d0, float d1, int lab) {
    float pos = lab ? d1 : d0;
    float neg = lab ? d0 : d1;
    float c1 = cos_fast(pos + MARGIN);
    float c0 = cos_fast(neg);
    float d  = (c0 - c1) * SCALE;         // ln - lp
    float t  = __expf(-fabsf(d));         // v_exp_f32
    float s  = __logf(1.0f + t);          // v_log_f32
    return fmaxf(d, 0.0f) + s;            // softplus(d) = logaddexp(lp,ln)-lp
}

__device__ __forceinline__ float quad_loss(float4 a, float4 b, int4 l) {
    float acc;
    acc  = sample_loss(a.x, b.x, l.x);
    acc += sample_loss(a.y, b.y, l.y);
    acc += sample_loss(a.z, b.z, l.z);
    acc += sample_loss(a.w, b.w, l.w);
    return acc;
}

template <int BS>
__device__ __forceinline__ float block_reduce(float acc) {
    #pragma unroll
    for (int off = 32; off > 0; off >>= 1)
        acc += __shfl_down(acc, off, 64);
    __shared__ float warp_sums[BS / 64];
    int wave = threadIdx.x >> 6;
    int lane = threadIdx.x & 63;
    if (lane == 0) warp_sums[wave] = acc;
    __syncthreads();
    if (threadIdx.x == 0) {
        float s = warp_sums[0];
        #pragma unroll
        for (int w = 1; w < BS / 64; ++w) s += warp_sums[w];
        return s;
    }
    return 0.0f;
}

__global__ __launch_bounds__(BLOCK) void loss_partial_kernel(
    const float* __restrict__ dist, const int* __restrict__ label,
    float* __restrict__ partial, int n)
{
    const int ngroups = n >> 2;  // float4 groups (N=2^24 -> 4M)
    const float4* __restrict__ row0 = reinterpret_cast<const float4*>(dist);
    const float4* __restrict__ row1 = reinterpret_cast<const float4*>(dist + n);
    const int4*   __restrict__ lab4 = reinterpret_cast<const int4*>(label);

    const int base = blockIdx.x * (BLOCK * GPT) + threadIdx.x;

    float acc = 0.0f;
    if (base + 3 * BLOCK < ngroups) {
        // 12 independent 16B loads issued as one cluster; sched_barrier pins
        // them before the compute so all 12 stay in flight (~12KB/wave).
        float4 a0 = row0[base];
        float4 a1 = row0[base + BLOCK];
        float4 a2 = row0[base + 2 * BLOCK];
        float4 a3 = row0[base + 3 * BLOCK];
        float4 b0 = row1[base];
        float4 b1 = row1[base + BLOCK];
        float4 b2 = row1[base + 2 * BLOCK];
        float4 b3 = row1[base + 3 * BLOCK];
        int4   l0 = lab4[base];
        int4   l1 = lab4[base + BLOCK];
        int4   l2 = lab4[base + 2 * BLOCK];
        int4   l3 = lab4[base + 3 * BLOCK];
        __builtin_amdgcn_sched_barrier(0);
        acc  = quad_loss(a0, b0, l0);
        acc += quad_loss(a1, b1, l1);
        acc += quad_loss(a2, b2, l2);
        acc += quad_loss(a3, b3, l3);
    } else {
        #pragma unroll
        for (int k = 0; k < GPT; ++k) {
            int g = base + k * BLOCK;
            if (g < ngroups) acc += quad_loss(row0[g], row1[g], lab4[g]);
        }
    }

    float s = block_reduce<BLOCK>(acc);
    if (threadIdx.x == 0) partial[blockIdx.x] = s;
}

constexpr int RBLOCK = 1024;
__global__ __launch_bounds__(RBLOCK) void reduce_partials_kernel(
    const float* __restrict__ partial, float* __restrict__ out, int nparts)
{
    float acc = 0.0f;
    for (int i = threadIdx.x; i < nparts; i += RBLOCK) acc += partial[i];
    float s = block_reduce<RBLOCK>(acc);
    if (threadIdx.x == 0) out[0] = s;
}

extern "C" void kernel_launch(void* const* d_in, const int* in_sizes, int n_in,
                              void* d_out, int out_size, void* d_ws, size_t ws_size,
                              hipStream_t stream) {
    const float* dist  = (const float*)d_in[0];
    const int*   label = (const int*)d_in[1];
    float* out = (float*)d_out;
    float* partial = (float*)d_ws;

    const int n = in_sizes[0] / 2;          // N samples (dist is 2 x N)
    const int ngroups = n >> 2;             // float4 groups
    const int tile = BLOCK * GPT;
    const int grid = (ngroups + tile - 1) / tile;  // 4096 for N=2^24

    loss_partial_kernel<<<grid, BLOCK, 0, stream>>>(dist, label, partial, n);
    reduce_partials_kernel<<<1, RBLOCK, 0, stream>>>(partial, out, grid);
}

// Round 5
// 38.133 us; speedup vs baseline: 1.1431x; 1.0019x over previous
//
#include <hip/hip_runtime.h>

#define SCALE 64.0f
#define MARGIN 0.5f

constexpr int BLOCK = 256;
constexpr int GPT = 4;  // float4-groups per thread -> 12 independent 16B loads

typedef float f32x4 __attribute__((ext_vector_type(4)));
typedef int   i32x4 __attribute__((ext_vector_type(4)));

// cos(x) radians via HW TRANS pipe (v_cos_f32 takes revolutions).
__device__ __forceinline__ float cos_fast(float x) {
    float r = x * 0.15915494309189535f;   // radians -> revolutions
    r = r - floorf(r);                    // v_fract_f32
    return __builtin_amdgcn_cosf(r);      // v_cos_f32
}

__device__ __forceinline__ float sample_loss(float d0, float d1, int lab) {
    float pos = lab ? d1 : d0;
    float neg = lab ? d0 : d1;
    float c1 = cos_fast(pos + MARGIN);
    float c0 = cos_fast(neg);
    float d  = (c0 - c1) * SCALE;         // ln - lp
    float t  = __expf(-fabsf(d));         // v_exp_f32
    float s  = __logf(1.0f + t);          // v_log_f32
    return fmaxf(d, 0.0f) + s;            // softplus(d) = logaddexp(lp,ln)-lp
}

__device__ __forceinline__ float quad_loss(f32x4 a, f32x4 b, i32x4 l) {
    float acc;
    acc  = sample_loss(a.x, b.x, l.x);
    acc += sample_loss(a.y, b.y, l.y);
    acc += sample_loss(a.z, b.z, l.z);
    acc += sample_loss(a.w, b.w, l.w);
    return acc;
}

template <int BS>
__device__ __forceinline__ float block_reduce(float acc) {
    #pragma unroll
    for (int off = 32; off > 0; off >>= 1)
        acc += __shfl_down(acc, off, 64);
    __shared__ float warp_sums[BS / 64];
    int wave = threadIdx.x >> 6;
    int lane = threadIdx.x & 63;
    if (lane == 0) warp_sums[wave] = acc;
    __syncthreads();
    if (threadIdx.x == 0) {
        float s = warp_sums[0];
        #pragma unroll
        for (int w = 1; w < BS / 64; ++w) s += warp_sums[w];
        return s;
    }
    return 0.0f;
}

__global__ __launch_bounds__(BLOCK) void loss_partial_kernel(
    const float* __restrict__ dist, const int* __restrict__ label,
    float* __restrict__ partial, int n)
{
    const int ngroups = n >> 2;  // float4 groups (N=2^24 -> 4M)
    const f32x4* __restrict__ row0 = reinterpret_cast<const f32x4*>(dist);
    const f32x4* __restrict__ row1 = reinterpret_cast<const f32x4*>(dist + n);
    const i32x4* __restrict__ lab4 = reinterpret_cast<const i32x4*>(label);

    const int base = blockIdx.x * (BLOCK * GPT) + threadIdx.x;

    float acc = 0.0f;
    if (base + 3 * BLOCK < ngroups) {
        f32x4 a0 = row0[base];
        f32x4 a1 = row0[base + BLOCK];
        f32x4 a2 = row0[base + 2 * BLOCK];
        f32x4 a3 = row0[base + 3 * BLOCK];
        f32x4 b0 = row1[base];
        f32x4 b1 = row1[base + BLOCK];
        f32x4 b2 = row1[base + 2 * BLOCK];
        f32x4 b3 = row1[base + 3 * BLOCK];
        i32x4 l0 = lab4[base];
        i32x4 l1 = lab4[base + BLOCK];
        i32x4 l2 = lab4[base + 2 * BLOCK];
        i32x4 l3 = lab4[base + 3 * BLOCK];
        // Pin all 12 load results as simultaneously-live registers: the
        // compiler must issue all 12 global_load_dwordx4 before this point,
        // giving 12 KB in flight per wave (true MLP, ~240 KB/CU).
        asm volatile("" : "+v"(a0), "+v"(a1), "+v"(a2), "+v"(a3),
                          "+v"(b0), "+v"(b1), "+v"(b2), "+v"(b3),
                          "+v"(l0), "+v"(l1), "+v"(l2), "+v"(l3));
        acc  = quad_loss(a0, b0, l0);
        acc += quad_loss(a1, b1, l1);
        acc += quad_loss(a2, b2, l2);
        acc += quad_loss(a3, b3, l3);
    } else {
        #pragma unroll
        for (int k = 0; k < GPT; ++k) {
            int g = base + k * BLOCK;
            if (g < ngroups) acc += quad_loss(row0[g], row1[g], lab4[g]);
        }
    }

    float s = block_reduce<BLOCK>(acc);
    if (threadIdx.x == 0) partial[blockIdx.x] = s;
}

constexpr int RBLOCK = 1024;
__global__ __launch_bounds__(RBLOCK) void reduce_partials_kernel(
    const float* __restrict__ partial, float* __restrict__ out, int nparts)
{
    float acc = 0.0f;
    for (int i = threadIdx.x; i < nparts; i += RBLOCK) acc += partial[i];
    float s = block_reduce<RBLOCK>(acc);
    if (threadIdx.x == 0) out[0] = s;
}

extern "C" void kernel_launch(void* const* d_in, const int* in_sizes, int n_in,
                              void* d_out, int out_size, void* d_ws, size_t ws_size,
                              hipStream_t stream) {
    const float* dist  = (const float*)d_in[0];
    const int*   label = (const int*)d_in[1];
    float* out = (float*)d_out;
    float* partial = (float*)d_ws;

    const int n = in_sizes[0] / 2;          // N samples (dist is 2 x N)
    const int ngroups = n >> 2;             // float4 groups
    const int tile = BLOCK * GPT;
    const int grid = (ngroups + tile - 1) / tile;  // 4096 for N=2^24

    loss_partial_kernel<<<grid, BLOCK, 0, stream>>>(dist, label, partial, n);
    reduce_partials_kernel<<<1, RBLOCK, 0, stream>>>(partial, out, grid);
}

// Round 7
// 38.082 us; speedup vs baseline: 1.1446x; 1.0013x over previous
//
#include <hip/hip_runtime.h>

#define SCALE 64.0f
#define MARGIN 0.5f

constexpr int BLOCK = 256;
constexpr int GPT = 4;  // float4-groups per thread -> 12 independent 16B loads

typedef float f32x4 __attribute__((ext_vector_type(4)));
typedef int   i32x4 __attribute__((ext_vector_type(4)));

// cos(x) radians via HW TRANS pipe (v_cos_f32 takes revolutions).
__device__ __forceinline__ float cos_fast(float x) {
    float r = x * 0.15915494309189535f;   // radians -> revolutions
    r = r - floorf(r);                    // v_fract_f32
    return __builtin_amdgcn_cosf(r);      // v_cos_f32
}

__device__ __forceinline__ float sample_loss(float d0, float d1, int lab) {
    float pos = lab ? d1 : d0;
    float neg = lab ? d0 : d1;
    float c1 = cos_fast(pos + MARGIN);
    float c0 = cos_fast(neg);
    float d  = (c0 - c1) * SCALE;         // ln - lp
    float t  = __expf(-fabsf(d));         // v_exp_f32
    float s  = __logf(1.0f + t);          // v_log_f32
    return fmaxf(d, 0.0f) + s;            // softplus(d) = logaddexp(lp,ln)-lp
}

__device__ __forceinline__ float quad_loss(f32x4 a, f32x4 b, i32x4 l) {
    float acc;
    acc  = sample_loss(a.x, b.x, l.x);
    acc += sample_loss(a.y, b.y, l.y);
    acc += sample_loss(a.z, b.z, l.z);
    acc += sample_loss(a.w, b.w, l.w);
    return acc;
}

template <int BS>
__device__ __forceinline__ float block_reduce(float acc) {
    #pragma unroll
    for (int off = 32; off > 0; off >>= 1)
        acc += __shfl_down(acc, off, 64);
    __shared__ float warp_sums[BS / 64];
    int wave = threadIdx.x >> 6;
    int lane = threadIdx.x & 63;
    if (lane == 0) warp_sums[wave] = acc;
    __syncthreads();
    if (threadIdx.x == 0) {
        float s = warp_sums[0];
        #pragma unroll
        for (int w = 1; w < BS / 64; ++w) s += warp_sums[w];
        return s;
    }
    return 0.0f;
}

__global__ __launch_bounds__(BLOCK) void loss_partial_kernel(
    const float* __restrict__ dist, const int* __restrict__ label,
    float* __restrict__ partial, int n)
{
    const int ngroups = n >> 2;  // float4 groups (N=2^24 -> 4M)
    const int g0 = blockIdx.x * (GPT * BLOCK) + threadIdx.x;

    float acc = 0.0f;
    if (g0 + 3 * BLOCK < ngroups) {
        const float* p0 = dist;
        const float* p1 = dist + n;
        const int*   pl = label;
        // group k (k=0..3) at byte offset g0*16 + k*4096; 13-bit signed imm
        // covers -4096..4095 so bias two voffsets by +4096.
        int voffA = g0 * 16 + 4096;   // k=0 (imm -4096), k=1 (imm 0)
        int voffB = voffA + 8192;     // k=2 (imm -4096), k=3 (imm 0)
        f32x4 a0, a1, a2, a3, b0, b1, b2, b3;
        i32x4 l0, l1, l2, l3;
        // All 12 loads issued back-to-back, ONE vmcnt(0). Outputs are
        // EARLY-CLOBBER ("=&v") so destinations cannot alias the voffset /
        // saddr inputs that later loads still read (R6 crash cause).
        asm volatile(
            "global_load_dwordx4 %[a0], %[vA], %[p0] offset:-4096\n\t"
            "global_load_dwordx4 %[a1], %[vA], %[p0]\n\t"
            "global_load_dwordx4 %[a2], %[vB], %[p0] offset:-4096\n\t"
            "global_load_dwordx4 %[a3], %[vB], %[p0]\n\t"
            "global_load_dwordx4 %[b0], %[vA], %[p1] offset:-4096\n\t"
            "global_load_dwordx4 %[b1], %[vA], %[p1]\n\t"
            "global_load_dwordx4 %[b2], %[vB], %[p1] offset:-4096\n\t"
            "global_load_dwordx4 %[b3], %[vB], %[p1]\n\t"
            "global_load_dwordx4 %[l0], %[vA], %[pl] offset:-4096\n\t"
            "global_load_dwordx4 %[l1], %[vA], %[pl]\n\t"
            "global_load_dwordx4 %[l2], %[vB], %[pl] offset:-4096\n\t"
            "global_load_dwordx4 %[l3], %[vB], %[pl]\n\t"
            "s_waitcnt vmcnt(0)"
            : [a0]"=&v"(a0), [a1]"=&v"(a1), [a2]"=&v"(a2), [a3]"=&v"(a3),
              [b0]"=&v"(b0), [b1]"=&v"(b1), [b2]"=&v"(b2), [b3]"=&v"(b3),
              [l0]"=&v"(l0), [l1]"=&v"(l1), [l2]"=&v"(l2), [l3]"=&v"(l3)
            : [vA]"v"(voffA), [vB]"v"(voffB),
              [p0]"s"(p0), [p1]"s"(p1), [pl]"s"(pl));
        acc  = quad_loss(a0, b0, l0);
        acc += quad_loss(a1, b1, l1);
        acc += quad_loss(a2, b2, l2);
        acc += quad_loss(a3, b3, l3);
    } else {
        const f32x4* __restrict__ row0 = reinterpret_cast<const f32x4*>(dist);
        const f32x4* __restrict__ row1 = reinterpret_cast<const f32x4*>(dist + n);
        const i32x4* __restrict__ lab4 = reinterpret_cast<const i32x4*>(label);
        #pragma unroll
        for (int k = 0; k < GPT; ++k) {
            int g = g0 + k * BLOCK;
            if (g < ngroups) acc += quad_loss(row0[g], row1[g], lab4[g]);
        }
    }

    float s = block_reduce<BLOCK>(acc);
    if (threadIdx.x == 0) partial[blockIdx.x] = s;
}

constexpr int RBLOCK = 1024;
__global__ __launch_bounds__(RBLOCK) void reduce_partials_kernel(
    const float* __restrict__ partial, float* __restrict__ out, int nparts)
{
    float acc = 0.0f;
    for (int i = threadIdx.x; i < nparts; i += RBLOCK) acc += partial[i];
    float s = block_reduce<RBLOCK>(acc);
    if (threadIdx.x == 0) out[0] = s;
}

extern "C" void kernel_launch(void* const* d_in, const int* in_sizes, int n_in,
                              void* d_out, int out_size, void* d_ws, size_t ws_size,
                              hipStream_t stream) {
    const float* dist  = (const float*)d_in[0];
    const int*   label = (const int*)d_in[1];
    float* out = (float*)d_out;
    float* partial = (float*)d_ws;

    const int n = in_sizes[0] / 2;          // N samples (dist is 2 x N)
    const int ngroups = n >> 2;             // float4 groups
    const int tile = BLOCK * GPT;
    const int grid = (ngroups + tile - 1) / tile;  // 4096 for N=2^24

    loss_partial_kernel<<<grid, BLOCK, 0, stream>>>(dist, label, partial, n);
    reduce_partials_kernel<<<1, RBLOCK, 0, stream>>>(partial, out, grid);
}